// Round 8
// baseline (1255.971 us; speedup 1.0000x reference)
//
#include <hip/hip_runtime.h>

#define P_TOT 65536
#define DIM   384
#define KCL   64
#define ITERS 10
#define BPTS  256            // points per block (fused / labelgather); grid 256
#define NSB   8              // partial sum buffers (atomic contention /8)
#define BK    16             // k-tile depth (double buffered, 1 barrier/tile)
#define NKT   (DIM / BK)     // 24
#define LKA   20             // A row pad: 20*4=80B, %16==0 (b128-aligned rows)
#define LKB   68             // B row pad (k-major), 272B %16==0

// d_ws layout (floats):
// centers[24576] | cnorm[64] | cnt[64] | CW[24576] | sums[8][24576]  ~= 983 KB

// centers0 = points[:64]; cnorm[c] = ||center||^2 ; zero cnt + all sum buffers
__global__ __launch_bounds__(384) void init_kernel(const float* __restrict__ x,
                                                   float* __restrict__ centers,
                                                   float* __restrict__ cnorm,
                                                   float* __restrict__ cnt,
                                                   float* __restrict__ sums) {
    __shared__ float red[384];
    const int c = blockIdx.x, t = threadIdx.x;
    float v = x[(size_t)c * DIM + t];
    centers[(size_t)c * DIM + t] = v;
#pragma unroll
    for (int b = 0; b < NSB; ++b) sums[(size_t)b * KCL * DIM + (size_t)c * DIM + t] = 0.f;
    if (t == 0) cnt[c] = 0.f;
    red[t] = v * v;
    __syncthreads();
    if (t < 128) red[t] = red[t] + red[t + 128] + red[t + 256];
    __syncthreads();
    for (int s = 64; s > 0; s >>= 1) {
        if (t < s) red[t] += red[t + s];
        __syncthreads();
    }
    if (t == 0) cnorm[c] = red[0];
}

// ---- GEMM+argmin body: 256 points x 64 clusters, 512 threads, 8pt x 4cl
// per thread. A point-major [pt][k]; B k-major. Per kq: 4 B-frags hoisted,
// then 8x {1 A-read -> 16 FMA} (live regs ~85, no spill at 128-cap).
// k strictly ascending, one fmac per k => labels bit-identical to prior
// passing rounds. Produces lab[BPTS] in LDS.
#define GEMM_ARGMIN_BODY(X, CENTERS, CNORM)                                          \
    const int t   = threadIdx.x;                                                     \
    const int cg  = t & 15;          /* clusters cg*4..cg*4+3 */                     \
    const int pg  = t >> 4;          /* 0..31: points pg*8..pg*8+7 */                \
    const int p0  = blockIdx.x * BPTS;                                               \
    const int spt = t >> 1;          /* A staging: point 0..255 */                   \
    const int sah = (t & 1) * 8;     /* A staging: k-half {0,8} */                   \
    const int sbc = t >> 3;          /* B staging: cluster 0..63 */                  \
    const int sbk = (t & 7) * 2;     /* B staging: k offset {0,2,..,14} */           \
    if (t < KCL) scn[t] = (CNORM)[t];                                                \
    float acc[8][4];                                                                 \
    _Pragma("unroll")                                                                \
    for (int i = 0; i < 8; ++i)                                                      \
        _Pragma("unroll")                                                            \
        for (int j = 0; j < 4; ++j) acc[i][j] = 0.f;                                 \
    const float* xrow = (X) + (size_t)(p0 + spt) * DIM;                              \
    const float* crow = (CENTERS) + (size_t)sbc * DIM;                               \
    float4 ra0 = *(const float4*)(xrow + sah);                                       \
    float4 ra1 = *(const float4*)(xrow + sah + 4);                                   \
    float2 rb  = *(const float2*)(crow + sbk);                                       \
    for (int kt = 0; kt < NKT; ++kt) {                                               \
        const int cur = kt & 1;                                                      \
        *(float4*)&At[cur][spt][sah + 0] = ra0;                                      \
        *(float4*)&At[cur][spt][sah + 4] = ra1;                                      \
        Bt[cur][sbk + 0][sbc] = rb.x;  Bt[cur][sbk + 1][sbc] = rb.y;                 \
        if (kt + 1 < NKT) {            /* prefetch next tile into regs */            \
            const int k0 = (kt + 1) * BK;                                            \
            ra0 = *(const float4*)(xrow + k0 + sah);                                 \
            ra1 = *(const float4*)(xrow + k0 + sah + 4);                             \
            rb  = *(const float2*)(crow + k0 + sbk);                                 \
        }                                                                            \
        __syncthreads();               /* single barrier per tile (2-deep dbuf) */   \
        _Pragma("unroll")                                                            \
        for (int kq = 0; kq < 4; ++kq) {                                             \
            const float4 bf0 = *(const float4*)&Bt[cur][kq * 4 + 0][cg * 4];         \
            const float4 bf1 = *(const float4*)&Bt[cur][kq * 4 + 1][cg * 4];         \
            const float4 bf2 = *(const float4*)&Bt[cur][kq * 4 + 2][cg * 4];         \
            const float4 bf3 = *(const float4*)&Bt[cur][kq * 4 + 3][cg * 4];         \
            _Pragma("unroll")                                                        \
            for (int i = 0; i < 8; ++i) {                                            \
                const float4 a4 = *(const float4*)&At[cur][pg * 8 + i][kq * 4];      \
                acc[i][0] += a4.x * bf0.x; acc[i][1] += a4.x * bf0.y;                \
                acc[i][2] += a4.x * bf0.z; acc[i][3] += a4.x * bf0.w;                \
                acc[i][0] += a4.y * bf1.x; acc[i][1] += a4.y * bf1.y;                \
                acc[i][2] += a4.y * bf1.z; acc[i][3] += a4.y * bf1.w;                \
                acc[i][0] += a4.z * bf2.x; acc[i][1] += a4.z * bf2.y;                \
                acc[i][2] += a4.z * bf2.z; acc[i][3] += a4.z * bf2.w;                \
                acc[i][0] += a4.w * bf3.x; acc[i][1] += a4.w * bf3.y;                \
                acc[i][2] += a4.w * bf3.z; acc[i][3] += a4.w * bf3.w;                \
            }                                                                        \
        }                                                                            \
    }                                                                                \
    {                                                                                \
        float cn[4];                                                                 \
        _Pragma("unroll")                                                            \
        for (int j = 0; j < 4; ++j) cn[j] = scn[cg * 4 + j];                         \
        _Pragma("unroll")                                                            \
        for (int i = 0; i < 8; ++i) {                                                \
            float bvv = 3.4e38f; int bc = 0;                                         \
            _Pragma("unroll")                                                        \
            for (int j = 0; j < 4; ++j) {                                            \
                float d = cn[j] - 2.0f * acc[i][j];                                  \
                if (d < bvv) { bvv = d; bc = cg * 4 + j; }  /* lowest idx ties */    \
            }                                                                        \
            _Pragma("unroll")                                                        \
            for (int m = 1; m < 16; m <<= 1) {  /* reduce over 16 owner lanes */     \
                const float ov = __shfl_xor(bvv, m, 64);                             \
                const int   oc = __shfl_xor(bc, m, 64);                              \
                if (ov < bvv || (ov == bvv && oc < bc)) { bvv = ov; bc = oc; }       \
            }                                                                        \
            if ((t & 15) == 0) lab[pg * 8 + i] = bc;                                 \
        }                                                                            \
    }                                                                                \
    __syncthreads();

// Fused assign + accumulate: GEMM/argmin (labels stay in LDS), counting sort,
// sorted-walk register accumulation, flush to NSB partial buffers.
// ~53KB LDS -> 2 blocks/CU: co-resident blocks overlap GEMM and accum phases.
__global__ __launch_bounds__(512, 4) void fused_kernel(const float* __restrict__ x,
                                                       const float* __restrict__ centers,
                                                       const float* __restrict__ cnorm,
                                                       float* __restrict__ sums,
                                                       float* __restrict__ cnt) {
    __shared__ float At[2][BPTS][LKA];  // 41 KB
    __shared__ float Bt[2][BK][LKB];    // 8.7 KB
    __shared__ float scn[KCL];
    __shared__ int   lab[BPTS];
    __shared__ int   lcnt[KCL];
    __shared__ int   lstart[KCL + 1];
    __shared__ int   lcur[KCL];
    __shared__ int   order[BPTS];

    if (threadIdx.x < KCL) lcnt[threadIdx.x] = 0;

    GEMM_ARGMIN_BODY(x, centers, cnorm)

    int myl = -1;
    if (t < BPTS) {
        myl = lab[t];
        atomicAdd(&lcnt[myl], 1);            // native int LDS atomic
    }
    __syncthreads();
    if (t < 64) {                            // wave 0: inclusive shfl scan
        int v = lcnt[t];
        int s = v;
#pragma unroll
        for (int d = 1; d < 64; d <<= 1) {
            int u = __shfl_up(s, d, 64);
            if (t >= d) s += u;
        }
        lstart[t] = s - v;
        lcur[t] = s - v;
        if (t == 63) lstart[64] = s;
    }
    __syncthreads();
    if (t < BPTS) {
        int pos = atomicAdd(&lcur[myl], 1);
        order[pos] = t;
    }
    __syncthreads();

    if (t < DIM) {                           // thread t owns dim t
        const float* xb = x + (size_t)p0 * DIM;
        float* sb = sums + (size_t)(blockIdx.x & (NSB - 1)) * KCL * DIM;
        int   curc = lab[order[0]];
        float run  = 0.f;
        for (int j0 = 0; j0 < BPTS; j0 += 8) {
            float v[8]; int cc[8];
#pragma unroll
            for (int u = 0; u < 8; ++u) {    // 8 independent loads in flight
                const int p = order[j0 + u];
                cc[u] = lab[p];
                v[u]  = xb[(size_t)p * DIM + t];
            }
#pragma unroll
            for (int u = 0; u < 8; ++u) {    // uniform branch (block-wide data)
                if (cc[u] != curc) {
                    atomicAdd(&sb[curc * DIM + t], run);
                    run = 0.f; curc = cc[u];
                }
                run += v[u];
            }
        }
        atomicAdd(&sb[curc * DIM + t], run);
    }
    if (t < KCL && lcnt[t] > 0) atomicAdd(&cnt[t], (float)lcnt[t]);
}

// final pass: GEMM/argmin, then write out[p][:] = CW[lab[p]][:] directly
// (CW is 96KB, L2-hot). No labels round-trip, no separate gather launch.
__global__ __launch_bounds__(512, 4) void labelgather_kernel(const float* __restrict__ x,
                                                             const float* __restrict__ centers,
                                                             const float* __restrict__ cnorm,
                                                             const float* __restrict__ CW,
                                                             float* __restrict__ out) {
    __shared__ float At[2][BPTS][LKA];
    __shared__ float Bt[2][BK][LKB];
    __shared__ float scn[KCL];
    __shared__ int   lab[BPTS];

    GEMM_ARGMIN_BODY(x, centers, cnorm)

    // 256 rows x 96 float4 = 24576 float4 chunks; 48 per thread.
    const float4* CW4 = (const float4*)CW;
    float4* out4 = (float4*)(out + (size_t)p0 * DIM);
#pragma unroll 4
    for (int r = 0; r < 48; ++r) {
        const int q  = r * 512 + t;
        const int pp = q / 96;
        const int jg = q - pp * 96;
        out4[(size_t)pp * 96 + jg] = CW4[(size_t)lab[pp] * 96 + jg];
    }
}

// centers[c] = cnt>0 ? sum(partials)/cnt : old ; cnorm ; re-zero partials/cnt
__global__ __launch_bounds__(384) void update_kernel(float* __restrict__ sums,
                                                     float* __restrict__ cnt,
                                                     float* __restrict__ centers,
                                                     float* __restrict__ cnorm) {
    __shared__ float red[384];
    const int c = blockIdx.x, t = threadIdx.x;
    float s = 0.f;
#pragma unroll
    for (int b = 0; b < NSB; ++b) {
        const size_t idx = (size_t)b * KCL * DIM + (size_t)c * DIM + t;
        s += sums[idx];
        sums[idx] = 0.f;
    }
    float n = cnt[c];
    float oldv = centers[(size_t)c * DIM + t];
    float nc = (n > 0.f) ? (s / n) : oldv;
    centers[(size_t)c * DIM + t] = nc;
    red[t] = nc * nc;
    __syncthreads();
    if (t == 0) cnt[c] = 0.f;   // after barrier: all reads of cnt[c] done
    if (t < 128) red[t] = red[t] + red[t + 128] + red[t + 256];
    __syncthreads();
    for (int st = 64; st > 0; st >>= 1) {
        if (t < st) red[t] += red[t + st];
        __syncthreads();
    }
    if (t == 0) cnorm[c] = red[0];
}

// CW[c][j] = b[j] + sum_d centers[c][d] * W[j][d]
__global__ __launch_bounds__(384) void cw_kernel(const float* __restrict__ centers,
                                                 const float* __restrict__ W,
                                                 const float* __restrict__ b,
                                                 float* __restrict__ CW) {
    __shared__ float cs[DIM];
    const int c = blockIdx.x, j = threadIdx.x;
    cs[j] = centers[(size_t)c * DIM + j];
    __syncthreads();
    float acc = b[j];
    const float* wr = W + (size_t)j * DIM;
    for (int d4 = 0; d4 < 96; ++d4) {
        float4 v = *(const float4*)(wr + d4 * 4);
        acc += cs[d4 * 4 + 0] * v.x + cs[d4 * 4 + 1] * v.y
             + cs[d4 * 4 + 2] * v.z + cs[d4 * 4 + 3] * v.w;
    }
    CW[(size_t)c * DIM + j] = acc;
}

extern "C" void kernel_launch(void* const* d_in, const int* in_sizes, int n_in,
                              void* d_out, int out_size, void* d_ws, size_t ws_size,
                              hipStream_t stream) {
    const float* x = (const float*)d_in[0];  // fp32 (16,4096,384)
    const float* W = (const float*)d_in[1];  // fp32 (384,384)
    const float* b = (const float*)d_in[2];  // fp32 (384,)
    float* out = (float*)d_out;              // fp32 (16,4096,384)

    float* centers = (float*)d_ws;                 // 64*384
    float* cnorm   = centers + KCL * DIM;          // 64
    float* cnt     = cnorm + KCL;                  // 64
    float* CW      = cnt + KCL;                    // 64*384
    float* sums    = CW + KCL * DIM;               // 8 * 64*384

    init_kernel<<<KCL, 384, 0, stream>>>(x, centers, cnorm, cnt, sums);
    for (int it = 0; it < ITERS; ++it) {
        fused_kernel<<<P_TOT / BPTS, 512, 0, stream>>>(x, centers, cnorm, sums, cnt);
        update_kernel<<<KCL, 384, 0, stream>>>(sums, cnt, centers, cnorm);
    }
    cw_kernel<<<KCL, 384, 0, stream>>>(centers, W, b, CW);
    labelgather_kernel<<<P_TOT / BPTS, 512, 0, stream>>>(x, centers, cnorm, CW, out);
}

// Round 9
// 1052.579 us; speedup vs baseline: 1.1932x; 1.1932x over previous
//
#include <hip/hip_runtime.h>

#define P_TOT 65536
#define DIM   384
#define KCL   64
#define ITERS 10
#define BPTS  256            // points per block (fused / labelgather); grid 256
#define NSB   8              // partial sum buffers (atomic contention /8)
#define BK    16             // k-tile depth (double buffered, 1 barrier/tile)
#define NKT   (DIM / BK)     // 24
#define LKA   20             // A row pad: 20*4=80B, %16==0 (b128-aligned rows)
#define LKB   68             // B row pad (k-major), 272B %16==0

// d_ws layout (floats):
// centers[24576] | cnorm[64] | cnt[64] | CW[24576] | sums[8][24576]  ~= 983 KB

// centers0 = points[:64]; cnorm[c] = ||center||^2 ; zero cnt + all sum buffers
__global__ __launch_bounds__(384) void init_kernel(const float* __restrict__ x,
                                                   float* __restrict__ centers,
                                                   float* __restrict__ cnorm,
                                                   float* __restrict__ cnt,
                                                   float* __restrict__ sums) {
    __shared__ float red[384];
    const int c = blockIdx.x, t = threadIdx.x;
    float v = x[(size_t)c * DIM + t];
    centers[(size_t)c * DIM + t] = v;
#pragma unroll
    for (int b = 0; b < NSB; ++b) sums[(size_t)b * KCL * DIM + (size_t)c * DIM + t] = 0.f;
    if (t == 0) cnt[c] = 0.f;
    red[t] = v * v;
    __syncthreads();
    if (t < 128) red[t] = red[t] + red[t + 128] + red[t + 256];
    __syncthreads();
    for (int s = 64; s > 0; s >>= 1) {
        if (t < s) red[t] += red[t + s];
        __syncthreads();
    }
    if (t == 0) cnorm[c] = red[0];
}

// ---- GEMM+argmin body: 256 points x 64 clusters, 512 threads, 8pt x 4cl
// per thread. A point-major [pt][k]; B k-major. Per kq: 4 B-frags hoisted,
// then 8x {1 A-read -> 16 FMA} (live regs ~90; needs the 128-VGPR cap,
// i.e. __launch_bounds__(512,2) — (512,4) caps at 64 and spills, r8 lesson).
// k strictly ascending, one fmac per k => labels bit-identical to prior
// passing rounds. Produces lab[BPTS] in LDS.
#define GEMM_ARGMIN_BODY(X, CENTERS, CNORM)                                          \
    const int t   = threadIdx.x;                                                     \
    const int cg  = t & 15;          /* clusters cg*4..cg*4+3 */                     \
    const int pg  = t >> 4;          /* 0..31: points pg*8..pg*8+7 */                \
    const int p0  = blockIdx.x * BPTS;                                               \
    const int spt = t >> 1;          /* A staging: point 0..255 */                   \
    const int sah = (t & 1) * 8;     /* A staging: k-half {0,8} */                   \
    const int sbc = t >> 3;          /* B staging: cluster 0..63 */                  \
    const int sbk = (t & 7) * 2;     /* B staging: k offset {0,2,..,14} */           \
    if (t < KCL) scn[t] = (CNORM)[t];                                                \
    float acc[8][4];                                                                 \
    _Pragma("unroll")                                                                \
    for (int i = 0; i < 8; ++i)                                                      \
        _Pragma("unroll")                                                            \
        for (int j = 0; j < 4; ++j) acc[i][j] = 0.f;                                 \
    const float* xrow = (X) + (size_t)(p0 + spt) * DIM;                              \
    const float* crow = (CENTERS) + (size_t)sbc * DIM;                               \
    float4 ra0 = *(const float4*)(xrow + sah);                                       \
    float4 ra1 = *(const float4*)(xrow + sah + 4);                                   \
    float2 rb  = *(const float2*)(crow + sbk);                                       \
    for (int kt = 0; kt < NKT; ++kt) {                                               \
        const int cur = kt & 1;                                                      \
        *(float4*)&At[cur][spt][sah + 0] = ra0;                                      \
        *(float4*)&At[cur][spt][sah + 4] = ra1;                                      \
        Bt[cur][sbk + 0][sbc] = rb.x;  Bt[cur][sbk + 1][sbc] = rb.y;                 \
        if (kt + 1 < NKT) {            /* prefetch next tile into regs */            \
            const int k0 = (kt + 1) * BK;                                            \
            ra0 = *(const float4*)(xrow + k0 + sah);                                 \
            ra1 = *(const float4*)(xrow + k0 + sah + 4);                             \
            rb  = *(const float2*)(crow + k0 + sbk);                                 \
        }                                                                            \
        __syncthreads();               /* single barrier per tile (2-deep dbuf) */   \
        _Pragma("unroll")                                                            \
        for (int kq = 0; kq < 4; ++kq) {                                             \
            const float4 bf0 = *(const float4*)&Bt[cur][kq * 4 + 0][cg * 4];         \
            const float4 bf1 = *(const float4*)&Bt[cur][kq * 4 + 1][cg * 4];         \
            const float4 bf2 = *(const float4*)&Bt[cur][kq * 4 + 2][cg * 4];         \
            const float4 bf3 = *(const float4*)&Bt[cur][kq * 4 + 3][cg * 4];         \
            _Pragma("unroll")                                                        \
            for (int i = 0; i < 8; ++i) {                                            \
                const float4 a4 = *(const float4*)&At[cur][pg * 8 + i][kq * 4];      \
                acc[i][0] += a4.x * bf0.x; acc[i][1] += a4.x * bf0.y;                \
                acc[i][2] += a4.x * bf0.z; acc[i][3] += a4.x * bf0.w;                \
                acc[i][0] += a4.y * bf1.x; acc[i][1] += a4.y * bf1.y;                \
                acc[i][2] += a4.y * bf1.z; acc[i][3] += a4.y * bf1.w;                \
                acc[i][0] += a4.z * bf2.x; acc[i][1] += a4.z * bf2.y;                \
                acc[i][2] += a4.z * bf2.z; acc[i][3] += a4.z * bf2.w;                \
                acc[i][0] += a4.w * bf3.x; acc[i][1] += a4.w * bf3.y;                \
                acc[i][2] += a4.w * bf3.z; acc[i][3] += a4.w * bf3.w;                \
            }                                                                        \
        }                                                                            \
    }                                                                                \
    {                                                                                \
        float cn[4];                                                                 \
        _Pragma("unroll")                                                            \
        for (int j = 0; j < 4; ++j) cn[j] = scn[cg * 4 + j];                         \
        _Pragma("unroll")                                                            \
        for (int i = 0; i < 8; ++i) {                                                \
            float bvv = 3.4e38f; int bc = 0;                                         \
            _Pragma("unroll")                                                        \
            for (int j = 0; j < 4; ++j) {                                            \
                float d = cn[j] - 2.0f * acc[i][j];                                  \
                if (d < bvv) { bvv = d; bc = cg * 4 + j; }  /* lowest idx ties */    \
            }                                                                        \
            _Pragma("unroll")                                                        \
            for (int m = 1; m < 16; m <<= 1) {  /* reduce over 16 owner lanes */     \
                const float ov = __shfl_xor(bvv, m, 64);                             \
                const int   oc = __shfl_xor(bc, m, 64);                              \
                if (ov < bvv || (ov == bvv && oc < bc)) { bvv = ov; bc = oc; }       \
            }                                                                        \
            if ((t & 15) == 0) lab[pg * 8 + i] = bc;                                 \
        }                                                                            \
    }                                                                                \
    __syncthreads();

// Fused assign + accumulate: GEMM/argmin (labels stay in LDS), counting sort,
// sorted-walk register accumulation, flush to NSB partial buffers.
// ~53KB LDS + 124 VGPR -> 2 blocks/CU: co-resident blocks overlap phases.
__global__ __launch_bounds__(512, 2) void fused_kernel(const float* __restrict__ x,
                                                       const float* __restrict__ centers,
                                                       const float* __restrict__ cnorm,
                                                       float* __restrict__ sums,
                                                       float* __restrict__ cnt) {
    __shared__ float At[2][BPTS][LKA];  // 41 KB
    __shared__ float Bt[2][BK][LKB];    // 8.7 KB
    __shared__ float scn[KCL];
    __shared__ int   lab[BPTS];
    __shared__ int   lcnt[KCL];
    __shared__ int   lstart[KCL + 1];
    __shared__ int   lcur[KCL];
    __shared__ int   order[BPTS];

    if (threadIdx.x < KCL) lcnt[threadIdx.x] = 0;

    GEMM_ARGMIN_BODY(x, centers, cnorm)

    int myl = -1;
    if (t < BPTS) {
        myl = lab[t];
        atomicAdd(&lcnt[myl], 1);            // native int LDS atomic
    }
    __syncthreads();
    if (t < 64) {                            // wave 0: inclusive shfl scan
        int v = lcnt[t];
        int s = v;
#pragma unroll
        for (int d = 1; d < 64; d <<= 1) {
            int u = __shfl_up(s, d, 64);
            if (t >= d) s += u;
        }
        lstart[t] = s - v;
        lcur[t] = s - v;
        if (t == 63) lstart[64] = s;
    }
    __syncthreads();
    if (t < BPTS) {
        int pos = atomicAdd(&lcur[myl], 1);
        order[pos] = t;
    }
    __syncthreads();

    if (t < DIM) {                           // thread t owns dim t
        const float* xb = x + (size_t)p0 * DIM;
        float* sb = sums + (size_t)(blockIdx.x & (NSB - 1)) * KCL * DIM;
        int   curc = lab[order[0]];
        float run  = 0.f;
        for (int j0 = 0; j0 < BPTS; j0 += 8) {
            float v[8]; int cc[8];
#pragma unroll
            for (int u = 0; u < 8; ++u) {    // 8 independent loads in flight
                const int p = order[j0 + u];
                cc[u] = lab[p];
                v[u]  = xb[(size_t)p * DIM + t];
            }
#pragma unroll
            for (int u = 0; u < 8; ++u) {    // uniform branch (block-wide data)
                if (cc[u] != curc) {
                    atomicAdd(&sb[curc * DIM + t], run);
                    run = 0.f; curc = cc[u];
                }
                run += v[u];
            }
        }
        atomicAdd(&sb[curc * DIM + t], run);
    }
    if (t < KCL && lcnt[t] > 0) atomicAdd(&cnt[t], (float)lcnt[t]);
}

// final pass: GEMM/argmin, then write out[p][:] = CW[lab[p]][:] directly
// (CW is 96KB, L2-hot). No labels round-trip, no separate gather launch.
__global__ __launch_bounds__(512, 2) void labelgather_kernel(const float* __restrict__ x,
                                                             const float* __restrict__ centers,
                                                             const float* __restrict__ cnorm,
                                                             const float* __restrict__ CW,
                                                             float* __restrict__ out) {
    __shared__ float At[2][BPTS][LKA];
    __shared__ float Bt[2][BK][LKB];
    __shared__ float scn[KCL];
    __shared__ int   lab[BPTS];

    GEMM_ARGMIN_BODY(x, centers, cnorm)

    // 256 rows x 96 float4 = 24576 float4 chunks; 48 per thread.
    const float4* CW4 = (const float4*)CW;
    float4* out4 = (float4*)(out + (size_t)p0 * DIM);
#pragma unroll 4
    for (int r = 0; r < 48; ++r) {
        const int q  = r * 512 + t;
        const int pp = q / 96;
        const int jg = q - pp * 96;
        out4[(size_t)pp * 96 + jg] = CW4[(size_t)lab[pp] * 96 + jg];
    }
}

// centers[c] = cnt>0 ? sum(partials)/cnt : old ; cnorm ; re-zero partials/cnt
__global__ __launch_bounds__(384) void update_kernel(float* __restrict__ sums,
                                                     float* __restrict__ cnt,
                                                     float* __restrict__ centers,
                                                     float* __restrict__ cnorm) {
    __shared__ float red[384];
    const int c = blockIdx.x, t = threadIdx.x;
    float s = 0.f;
#pragma unroll
    for (int b = 0; b < NSB; ++b) {
        const size_t idx = (size_t)b * KCL * DIM + (size_t)c * DIM + t;
        s += sums[idx];
        sums[idx] = 0.f;
    }
    float n = cnt[c];
    float oldv = centers[(size_t)c * DIM + t];
    float nc = (n > 0.f) ? (s / n) : oldv;
    centers[(size_t)c * DIM + t] = nc;
    red[t] = nc * nc;
    __syncthreads();
    if (t == 0) cnt[c] = 0.f;   // after barrier: all reads of cnt[c] done
    if (t < 128) red[t] = red[t] + red[t + 128] + red[t + 256];
    __syncthreads();
    for (int st = 64; st > 0; st >>= 1) {
        if (t < st) red[t] += red[t + st];
        __syncthreads();
    }
    if (t == 0) cnorm[c] = red[0];
}

// CW[c][j] = b[j] + sum_d centers[c][d] * W[j][d]
__global__ __launch_bounds__(384) void cw_kernel(const float* __restrict__ centers,
                                                 const float* __restrict__ W,
                                                 const float* __restrict__ b,
                                                 float* __restrict__ CW) {
    __shared__ float cs[DIM];
    const int c = blockIdx.x, j = threadIdx.x;
    cs[j] = centers[(size_t)c * DIM + j];
    __syncthreads();
    float acc = b[j];
    const float* wr = W + (size_t)j * DIM;
    for (int d4 = 0; d4 < 96; ++d4) {
        float4 v = *(const float4*)(wr + d4 * 4);
        acc += cs[d4 * 4 + 0] * v.x + cs[d4 * 4 + 1] * v.y
             + cs[d4 * 4 + 2] * v.z + cs[d4 * 4 + 3] * v.w;
    }
    CW[(size_t)c * DIM + j] = acc;
}

extern "C" void kernel_launch(void* const* d_in, const int* in_sizes, int n_in,
                              void* d_out, int out_size, void* d_ws, size_t ws_size,
                              hipStream_t stream) {
    const float* x = (const float*)d_in[0];  // fp32 (16,4096,384)
    const float* W = (const float*)d_in[1];  // fp32 (384,384)
    const float* b = (const float*)d_in[2];  // fp32 (384,)
    float* out = (float*)d_out;              // fp32 (16,4096,384)

    float* centers = (float*)d_ws;                 // 64*384
    float* cnorm   = centers + KCL * DIM;          // 64
    float* cnt     = cnorm + KCL;                  // 64
    float* CW      = cnt + KCL;                    // 64*384
    float* sums    = CW + KCL * DIM;               // 8 * 64*384

    init_kernel<<<KCL, 384, 0, stream>>>(x, centers, cnorm, cnt, sums);
    for (int it = 0; it < ITERS; ++it) {
        fused_kernel<<<P_TOT / BPTS, 512, 0, stream>>>(x, centers, cnorm, sums, cnt);
        update_kernel<<<KCL, 384, 0, stream>>>(sums, cnt, centers, cnorm);
    }
    cw_kernel<<<KCL, 384, 0, stream>>>(centers, W, b, CW);
    labelgather_kernel<<<P_TOT / BPTS, 512, 0, stream>>>(x, centers, cnorm, CW, out);
}